// Round 8
// baseline (201.900 us; speedup 1.0000x reference)
//
#include <hip/hip_runtime.h>
#include <math.h>

// ---------------- types ----------------
typedef __attribute__((ext_vector_type(8))) short short8;
typedef __attribute__((ext_vector_type(4))) float f32x4;

#define NB 2
#define LQ 2048
#define LK 2048
#define DM 1024
#define NH 16
#define HD 64

__device__ __forceinline__ unsigned short f2bf(float f) {
    unsigned u = __builtin_bit_cast(unsigned, f);
    u = (u + 0x7FFFu + ((u >> 16) & 1u)) >> 16;
    return (unsigned short)u;
}

__device__ __forceinline__ void gload16(const void* g, void* l) {
    __builtin_amdgcn_global_load_lds(
        (const __attribute__((address_space(1))) void*)g,
        (__attribute__((address_space(3))) void*)l, 16, 0, 0);
}

__device__ __forceinline__ unsigned cvtpk(float a, float b) {
    unsigned r;
    asm("v_cvt_pk_bf16_f32 %0, %1, %2" : "=v"(r) : "v"(a), "v"(b));
    return r;
}

__device__ __forceinline__ float max3f(float a, float b, float c) {
    float r;
    asm("v_max3_f32 %0, %1, %2, %3" : "=v"(r) : "v"(a), "v"(b), "v"(c));
    return r;
}

// XOR-swizzled LDS accessors for [R][64] u16 tiles (row stride 128 B): 2-way max, free.
__device__ __forceinline__ short8 lds_load8(const unsigned short* base, int row, int col) {
    int byte = (row * 128 + col * 2) ^ ((row & 7) << 4);
    return *(const short8*)((const char*)base + byte);
}

// swizzled accessor for [R][32] u16 LDS tiles (row stride 64 B).
// XOR with (row>>2)&3: rows sharing (b0,b2,b3) differ only in b1 -> 2-way (free).
__device__ __forceinline__ short8 lds32(const unsigned short* base, int row, int col) {
    int byte = (row * 64 + col * 2) ^ (((row >> 2) & 3) << 4);
    return *(const short8*)((const char*)base + byte);
}

// ---------------- convert f32 -> bf16 ----------------
__global__ __launch_bounds__(256) void convertk(
    const float* __restrict__ q, const float* __restrict__ k,
    const float* __restrict__ wq, const float* __restrict__ wk,
    const float* __restrict__ wv, unsigned short* __restrict__ dst)
{
    long i4 = (long)blockIdx.x * 256 + threadIdx.x;
    long e = i4 * 4;
    if (e >= 11534336L) return;
    const float* src; long off;
    if (e < 4194304L)       { src = q;  off = e; }
    else if (e < 8388608L)  { src = k;  off = e - 4194304L; }
    else if (e < 9437184L)  { src = wq; off = e - 8388608L; }
    else if (e < 10485760L) { src = wk; off = e - 9437184L; }
    else                    { src = wv; off = e - 10485760L; }
    float4 v = *(const float4*)(src + off);
    ushort4 r;
    r.x = f2bf(v.x); r.y = f2bf(v.y); r.z = f2bf(v.z); r.w = f2bf(v.w);
    *(ushort4*)(dst + e) = r;
}

// ---------------- projection GEMM: C = A * B^T (bf16, K=1024, BK=32, LDS dbuf) ----------------
// z==2 (V projection) writes Vt transposed directly (fuses the old transposek kernel).
__device__ __forceinline__ void gemm_stage(
    const unsigned short* A, const unsigned short* B,
    unsigned short* As, unsigned short* Bs,
    int bm, int bn, int k0, int wave, int srow, int scol)
{
    const int K = DM;
    int i0 = wave, i1 = wave + 4;
    gload16(A + (size_t)(bm + i0 * 16 + srow) * K + k0 + scol, As + i0 * 512);
    gload16(B + (size_t)(bn + i0 * 16 + srow) * K + k0 + scol, Bs + i0 * 512);
    gload16(A + (size_t)(bm + i1 * 16 + srow) * K + k0 + scol, As + i1 * 512);
    gload16(B + (size_t)(bn + i1 * 16 + srow) * K + k0 + scol, Bs + i1 * 512);
}

__global__ __launch_bounds__(256) void gemm3(
    const unsigned short* __restrict__ Qb, const unsigned short* __restrict__ Kb,
    const unsigned short* __restrict__ Wqb, const unsigned short* __restrict__ Wkb,
    const unsigned short* __restrict__ Wvb,
    unsigned short* __restrict__ Qp, unsigned short* __restrict__ Kp, unsigned short* __restrict__ Vt)
{
    const unsigned short *A, *B;
    int z = blockIdx.z;
    if (z == 0)      { A = Qb; B = Wqb; }
    else if (z == 1) { A = Kb; B = Wkb; }
    else             { A = Kb; B = Wvb; }
    const int NN = DM;
    __shared__ unsigned short As[2][4096];  // [128][32] swizzled
    __shared__ unsigned short Bs[2][4096];
    int t = threadIdx.x, wave = t >> 6, lane = t & 63;
    int bm = blockIdx.x * 128, bn = blockIdx.y * 128;
    int wr = (wave >> 1) * 64, wc = (wave & 1) * 64;
    int srow = lane >> 2;                               // 0..15 within 16-row stripe
    int scol = ((lane & 3) ^ ((srow >> 2) & 3)) << 3;   // pre-swizzled source col (elems)
    int frow = lane & 15, fk = (lane >> 4) * 8;
    f32x4 zero = {0.f, 0.f, 0.f, 0.f};
    f32x4 acc[4][4];
    for (int i = 0; i < 4; i++) for (int j = 0; j < 4; j++) acc[i][j] = zero;

    gemm_stage(A, B, As[0], Bs[0], bm, bn, 0, wave, srow, scol);
    __syncthreads();
    for (int s = 0; s < 32; s++) {
        int cur = s & 1;
        if (s + 1 < 32)
            gemm_stage(A, B, As[cur ^ 1], Bs[cur ^ 1], bm, bn, (s + 1) * 32, wave, srow, scol);
        short8 af[4], bfr[4];
#pragma unroll
        for (int i = 0; i < 4; i++) af[i]  = lds32(As[cur], wr + i * 16 + frow, fk);
#pragma unroll
        for (int j = 0; j < 4; j++) bfr[j] = lds32(Bs[cur], wc + j * 16 + frow, fk);
#pragma unroll
        for (int i = 0; i < 4; i++)
#pragma unroll
            for (int j = 0; j < 4; j++)
                acc[i][j] = __builtin_amdgcn_mfma_f32_16x16x32_bf16(af[i], bfr[j], acc[i][j], 0, 0, 0);
        __syncthreads();
    }
    int ccol = lane & 15, crow = (lane >> 4) * 4;
    if (z < 2) {
        unsigned short* C = (z == 0) ? Qp : Kp;
#pragma unroll
        for (int i = 0; i < 4; i++)
#pragma unroll
            for (int j = 0; j < 4; j++) {
                int col = bn + wc + j * 16 + ccol;
#pragma unroll
                for (int r = 0; r < 4; r++) {
                    int row = bm + wr + i * 16 + crow + r;
                    C[(size_t)row * NN + col] = f2bf(acc[i][j][r]);
                }
            }
    } else {
        // transposed store: Vt[(n*DM + col)*LK + l], 4 consecutive rows -> ushort4
#pragma unroll
        for (int i = 0; i < 4; i++)
#pragma unroll
            for (int j = 0; j < 4; j++) {
                int col = bn + wc + j * 16 + ccol;
                int row0 = bm + wr + i * 16 + crow;       // multiple of 4, within one n
                int nn = row0 >> 11, l0 = row0 & 2047;
                ushort4 v4;
                v4.x = f2bf(acc[i][j][0]); v4.y = f2bf(acc[i][j][1]);
                v4.z = f2bf(acc[i][j][2]); v4.w = f2bf(acc[i][j][3]);
                *(ushort4*)&Vt[((size_t)(nn * DM + col)) * LK + l0] = v4;
            }
    }
}

// ---------------- flash attention v8: 4-wave blocks, LDS-staged K/V, lean softmax ----------------
// Q pre-scaled by c2 = log2e/sqrt(vlen) -> S arrives scaled (no per-phase muls).
// Row-sum l accumulated by ones-MFMA in o-row ownership (no sum tree, no shfl).
// Swapped mfma(K,Q): lane holds S-column for one q (q = qw + (lane&15)).

__device__ __forceinline__ void stage_kv64(
    const unsigned short* Kbase, const unsigned short* Vbase,
    unsigned short* KsB, unsigned short* VsB,
    int k0, int w, int srl, int scs)
{
#pragma unroll
    for (int ii = 0; ii < 2; ii++) {
        int r0 = (w + 4 * ii) * 8;   // 8-row stripe base
        gload16(Kbase + (size_t)(k0 + r0 + srl) * DM + scs, KsB + r0 * 64);
        gload16(Vbase + (size_t)(r0 + srl) * LK + k0 + scs, VsB + r0 * 64);
    }
}

__device__ __forceinline__ void softmax_pack(
    f32x4 (&sv)[4], unsigned short* PsW,
    int qw, int k0, int vlen,
    f32x4 (&o)[4], f32x4& lsum, float& m_run, int lane)
{
    const int c = lane & 15, g = lane >> 4;
    bool full = (k0 + 63 <= qw) && (k0 + 64 <= vlen);
    if (!full) {
        int q = qw + c;
#pragma unroll
        for (int kt = 0; kt < 4; kt++)
#pragma unroll
            for (int r = 0; r < 4; r++) {
                int kg = k0 + kt * 16 + g * 4 + r;
                if (kg > q || kg >= vlen) sv[kt][r] = -INFINITY;
            }
    }
    float mx = max3f(sv[0][0], sv[0][1], sv[0][2]);
    mx = max3f(mx, sv[0][3], sv[1][0]);
    mx = max3f(mx, sv[1][1], sv[1][2]);
    mx = max3f(mx, sv[1][3], sv[2][0]);
    mx = max3f(mx, sv[2][1], sv[2][2]);
    mx = max3f(mx, sv[2][3], sv[3][0]);
    mx = max3f(mx, sv[3][1], sv[3][2]);
    mx = fmaxf(mx, sv[3][3]);
    mx = fmaxf(mx, __shfl_xor(mx, 16));
    mx = fmaxf(mx, __shfl_xor(mx, 32));      // per-q max over tile (q shared by 4 lanes)
    // defer-max (T13): rescale only when max grew > 8 (P bounded by 2^8; S pre-scaled)
    if (__any(mx - m_run > 8.0f)) {
        float mn = fmaxf(m_run, mx);
        float al = __builtin_amdgcn_exp2f(m_run - mn);
        float alr[4];
#pragma unroll
        for (int r = 0; r < 4; r++) alr[r] = __shfl(al, 4 * g + r);
#pragma unroll
        for (int dt = 0; dt < 4; dt++)
#pragma unroll
            for (int r = 0; r < 4; r++) o[dt][r] *= alr[r];
#pragma unroll
        for (int r = 0; r < 4; r++) lsum[r] *= alr[r];
        m_run = mn;
    }
#pragma unroll
    for (int kt = 0; kt < 4; kt++)
#pragma unroll
        for (int r = 0; r < 4; r++)
            sv[kt][r] = __builtin_amdgcn_exp2f(sv[kt][r] - m_run);
#pragma unroll
    for (int kt = 0; kt < 4; kt++) {
        uint2 pw;
        pw.x = cvtpk(sv[kt][0], sv[kt][1]);
        pw.y = cvtpk(sv[kt][2], sv[kt][3]);
        int byte = (c * 128 + (kt * 16 + g * 4) * 2) ^ ((c & 7) << 4);
        *(uint2*)((char*)PsW + byte) = pw;
    }
}

__global__ __launch_bounds__(256, 4) void attnk(
    const unsigned short* __restrict__ Qp, const unsigned short* __restrict__ Kp,
    const unsigned short* __restrict__ Vt, const unsigned char* __restrict__ pm,
    float* __restrict__ out)
{
    __shared__ unsigned short Ks[2][4096];   // [64 k][64 d] swizzled, dbuf
    __shared__ unsigned short Vs[2][4096];   // [64 d][64 k] swizzled, dbuf
    __shared__ unsigned short Ps[4][1024];   // per-wave [16 q][64 k] swizzled
    int t = threadIdx.x, w = t >> 6, lane = t & 63;
    int bid = blockIdx.x;
    int nh = (bid & 7) * 4 + ((bid >> 3) & 3);
    int n = nh >> 4, h = nh & 15;
    int jj = (bid >> 5) & 7, rr = bid >> 8;
    int qc = (rr == 0) ? 31 - jj : (rr == 1) ? 16 + jj : (rr == 2) ? 15 - jj : jj;
    int qw = qc * 64 + 16 * w;
    const int c = lane & 15, g = lane >> 4, fk = g * 8;

    // valid length via popcount of padding mask
    int vlen;
    {
        const uint4* pmv = (const uint4*)(pm + (size_t)n * LK);
        uint4 a = pmv[lane * 2], b = pmv[lane * 2 + 1];
        int ones = __popc(a.x) + __popc(a.y) + __popc(a.z) + __popc(a.w)
                 + __popc(b.x) + __popc(b.y) + __popc(b.z) + __popc(b.w);
        int zeros = 32 - ones;
#pragma unroll
        for (int off = 1; off < 64; off <<= 1) zeros += __shfl_xor(zeros, off);
        vlen = zeros;
    }
    float c2 = 1.4426950408889634f / sqrtf((float)vlen);
    int kvt = (vlen + 63) >> 6;
    int nt = min(qc + 1, kvt);

    int srl = lane >> 3;
    int scs = ((lane & 7) ^ srl) << 3;   // pre-swizzled source column (elems)
    const unsigned short* Kbase = Kp + (size_t)n * LK * DM + h * HD;
    const unsigned short* Vbase = Vt + ((size_t)n * DM + h * HD) * LK;

    // Q fragments (B-operand: row = lane&15 -> q = qw + c), pre-scaled by c2
    const unsigned short* qp = Qp + (size_t)(n * LQ + qw + c) * DM + h * HD;
    short8 q0r = *(const short8*)(qp + fk), q1r = *(const short8*)(qp + 32 + fk);
    short8 q0, q1;
#pragma unroll
    for (int j = 0; j < 8; j++) {
        float f0 = __builtin_bit_cast(float, ((unsigned)(unsigned short)q0r[j]) << 16) * c2;
        float f1 = __builtin_bit_cast(float, ((unsigned)(unsigned short)q1r[j]) << 16) * c2;
        q0[j] = (short)f2bf(f0);
        q1[j] = (short)f2bf(f1);
    }
    short8 onesf;
#pragma unroll
    for (int j = 0; j < 8; j++) onesf[j] = (short)0x3F80;   // bf16 1.0

    f32x4 zero = {0.f, 0.f, 0.f, 0.f};
    f32x4 o[4] = {zero, zero, zero, zero};
    f32x4 lsum = zero;
    float m_run = -INFINITY;
    unsigned short* PsW = Ps[w];

    stage_kv64(Kbase, Vbase, Ks[0], Vs[0], 0, w, srl, scs);
    __syncthreads();

    for (int ti = 0; ti < nt; ti++) {
        int cur = ti & 1, k0 = ti * 64;
        if (ti + 1 < nt)
            stage_kv64(Kbase, Vbase, Ks[cur ^ 1], Vs[cur ^ 1], k0 + 64, w, srl, scs);

        f32x4 sv[4];
        __builtin_amdgcn_s_setprio(1);
#pragma unroll
        for (int kt = 0; kt < 4; kt++) {
            short8 kf0 = lds_load8(Ks[cur], kt * 16 + c, fk);
            short8 kf1 = lds_load8(Ks[cur], kt * 16 + c, 32 + fk);
            f32x4 z = zero;
            z = __builtin_amdgcn_mfma_f32_16x16x32_bf16(kf0, q0, z, 0, 0, 0);
            z = __builtin_amdgcn_mfma_f32_16x16x32_bf16(kf1, q1, z, 0, 0, 0);
            sv[kt] = z;
        }
        __builtin_amdgcn_s_setprio(0);

        softmax_pack(sv, PsW, qw, k0, vlen, o, lsum, m_run, lane);

        __builtin_amdgcn_s_setprio(1);
#pragma unroll
        for (int ks = 0; ks < 2; ks++) {
            short8 ap = lds_load8(PsW, c, ks * 32 + fk);
#pragma unroll
            for (int dt = 0; dt < 4; dt++) {
                short8 bv = lds_load8(Vs[cur], dt * 16 + c, ks * 32 + fk);
                o[dt] = __builtin_amdgcn_mfma_f32_16x16x32_bf16(ap, bv, o[dt], 0, 0, 0);
            }
            lsum = __builtin_amdgcn_mfma_f32_16x16x32_bf16(ap, onesf, lsum, 0, 0, 0);
        }
        __builtin_amdgcn_s_setprio(0);
        __syncthreads();   // staging of next tile drained + all waves done with cur
    }
    // epilogue: o and lsum share ownership (q = qw + 4g + r, d = h*64 + dt*16 + c)
#pragma unroll
    for (int dt = 0; dt < 4; dt++)
#pragma unroll
        for (int r = 0; r < 4; r++) {
            int q = qw + 4 * g + r;
            int d = h * HD + dt * 16 + c;
            out[((size_t)n * LQ + q) * DM + d] = o[dt][r] / lsum[r];
        }
}

// ---------------- launch ----------------
extern "C" void kernel_launch(void* const* d_in, const int* in_sizes, int n_in,
                              void* d_out, int out_size, void* d_ws, size_t ws_size,
                              hipStream_t stream) {
    const float* query = (const float*)d_in[0];
    const float* key   = (const float*)d_in[1];
    const float* Wq    = (const float*)d_in[2];
    const float* Wk    = (const float*)d_in[3];
    const float* Wv    = (const float*)d_in[4];
    const unsigned char* pmask = (const unsigned char*)d_in[6];
    float* out = (float*)d_out;

    char* ws = (char*)d_ws;
    unsigned short* bfbase = (unsigned short*)ws;
    unsigned short* Qb  = bfbase;                          // 4096x1024
    unsigned short* Kb  = bfbase + 4194304L;               // 4096x1024
    unsigned short* Wqb = bfbase + 8388608L;
    unsigned short* Wkb = bfbase + 9437184L;
    unsigned short* Wvb = bfbase + 10485760L;
    unsigned short* Qp  = (unsigned short*)(ws + 23068672L);
    unsigned short* Kp  = (unsigned short*)(ws + 31457280L);
    unsigned short* Vt  = (unsigned short*)(ws + 39845888L);   // [2][1024][2048]

    convertk<<<11264, 256, 0, stream>>>(query, key, Wq, Wk, Wv, bfbase);
    gemm3<<<dim3(32, 8, 3), 256, 0, stream>>>(Qb, Kb, Wqb, Wkb, Wvb, Qp, Kp, Vt);
    attnk<<<1024, 256, 0, stream>>>(Qp, Kp, Vt, pmask, out);
}